// Round 1
// 4188.180 us; speedup vs baseline: 1.0671x; 1.0671x over previous
//
#include <hip/hip_runtime.h>
#include <math.h>

#define NB 512
#define NN 256
#define N_ITERS 400
#define KAPPA_F 0.1f

typedef _Float16 half2_t __attribute__((ext_vector_type(2)));
typedef _Float16 half8_t __attribute__((ext_vector_type(8)));

__device__ inline float fdot2f(half2_t a, half2_t b, float c) {
#if __has_builtin(__builtin_amdgcn_fdot2)
  return __builtin_amdgcn_fdot2(a, b, c, false);
#else
  return (float)a.x * (float)b.x + (float)a.y * (float)b.y + c;
#endif
}

// R4 redesign: 512 threads/block (8 waves) -> waves_per_eu(2,2) -> 256-VGPR
// budget. Prior 1024-thread version was capped at 128 VGPRs with 96 persistent
// values -> allocator spilled ~1 GB to scratch inside the PGD loop
// (WRITE_SIZE=983MB vs 0.5MB of real output). New layout: each thread owns
// 4 rows x 32 cols: rows {lane,64+lane,128+lane,192+lane}, cols [32*wv,32*wv+32).
//   c##I##J  : float4, G1[row_I][32*wv+4J..+3]   (128 fp32 regs)
//   g##I##P##S : half2, G2 same block, half8-group P, pair S (64 regs)
// Persistent = 192 regs + ~50 temps < 256 -> no spills.
// Side benefit: uniform (broadcast) ds_read_b128 count drops 4x in both Gram
// (8/k vs 32/k) and matvec (12/iter vs 24/iter).
// Iteration = 2 barriers (was 3): wave 0 does combine+grad+projection inline.
// Exact early exit: if w is bitwise stationary the remaining iterations are
// identity -> break is exactly equivalent to running all 400.

#define ZERO1(I,J) c##I##J.x=0.f; c##I##J.y=0.f; c##I##J.z=0.f; c##I##J.w=0.f;
#define ZEROROW(I) ZERO1(I,0) ZERO1(I,1) ZERO1(I,2) ZERO1(I,3) ZERO1(I,4) ZERO1(I,5) ZERO1(I,6) ZERO1(I,7)
#define ZERO_ALL() ZEROROW(0) ZEROROW(1) ZEROROW(2) ZEROROW(3)

#define GACC(I,J) { c##I##J.x = fmaf(a##I, f##J.x, c##I##J.x); \
                    c##I##J.y = fmaf(a##I, f##J.y, c##I##J.y); \
                    c##I##J.z = fmaf(a##I, f##J.z, c##I##J.z); \
                    c##I##J.w = fmaf(a##I, f##J.w, c##I##J.w); }
#define GACCROW(I) GACC(I,0) GACC(I,1) GACC(I,2) GACC(I,3) GACC(I,4) GACC(I,5) GACC(I,6) GACC(I,7)

// Gram accumulate: c[I][J] += (SRC^T SRC)[rows][cols], fro += ||tile||^2
#define GRAM(SRC) do { \
  const float4* __restrict__ src4 = (const float4*)(SRC); \
  ZERO_ALL(); \
  fro = 0.f; \
  float4 st0 = src4[t], st1 = src4[512 + t]; \
  _Pragma("unroll 1") \
  for (int kt = 0; kt < 16; ++kt) { \
    __syncthreads(); \
    ((float4*)As)[t] = st0; \
    ((float4*)As)[512 + t] = st1; \
    fro += st0.x*st0.x + st0.y*st0.y + st0.z*st0.z + st0.w*st0.w; \
    fro += st1.x*st1.x + st1.y*st1.y + st1.z*st1.z + st1.w*st1.w; \
    __syncthreads(); \
    if (kt < 15) { st0 = src4[(kt + 1) * 1024 + t]; st1 = src4[(kt + 1) * 1024 + 512 + t]; } \
    _Pragma("unroll 2") \
    for (int k = 0; k < 16; ++k) { \
      const float* rowp = As + k * NN; \
      float a0 = rowp[lane]; \
      float a1 = rowp[64 + lane]; \
      float a2 = rowp[128 + lane]; \
      float a3 = rowp[192 + lane]; \
      const float4* rowp4 = (const float4*)(rowp + 32 * wv); \
      float4 f0 = rowp4[0], f1 = rowp4[1], f2 = rowp4[2], f3 = rowp4[3]; \
      float4 f4 = rowp4[4], f5 = rowp4[5], f6 = rowp4[6], f7 = rowp4[7]; \
      GACCROW(0) GACCROW(1) GACCROW(2) GACCROW(3) \
    } \
  } \
} while (0)

// fp32 c-pair -> 4 named half2 of (row I, half8-group P)
#define CVT1(I,P,CA,CB) { half2_t h; \
  h.x = (_Float16)c##I##CA.x; h.y = (_Float16)c##I##CA.y; g##I##P##0 = h; \
  h.x = (_Float16)c##I##CA.z; h.y = (_Float16)c##I##CA.w; g##I##P##1 = h; \
  h.x = (_Float16)c##I##CB.x; h.y = (_Float16)c##I##CB.y; g##I##P##2 = h; \
  h.x = (_Float16)c##I##CB.z; h.y = (_Float16)c##I##CB.w; g##I##P##3 = h; }
#define CVTROW(I) CVT1(I,0,0,1) CVT1(I,1,2,3) CVT1(I,2,4,5) CVT1(I,3,6,7)
#define CVT_ALL() CVTROW(0) CVTROW(1) CVTROW(2) CVTROW(3)

#define G1Q(I,J) p1##I = fmaf(c##I##J.x, wq##J.x, fmaf(c##I##J.y, wq##J.y, \
                     fmaf(c##I##J.z, wq##J.z, fmaf(c##I##J.w, wq##J.w, p1##I))));
#define G1ROW(I) G1Q(I,0) G1Q(I,1) G1Q(I,2) G1Q(I,3) G1Q(I,4) G1Q(I,5) G1Q(I,6) G1Q(I,7)

#define G2Q(I,P) \
  p2##I = fdot2f(g##I##P##0, __builtin_shufflevector(u##P, u##P, 0, 1), p2##I); \
  p2##I = fdot2f(g##I##P##1, __builtin_shufflevector(u##P, u##P, 2, 3), p2##I); \
  p2##I = fdot2f(g##I##P##2, __builtin_shufflevector(u##P, u##P, 4, 5), p2##I); \
  p2##I = fdot2f(g##I##P##3, __builtin_shufflevector(u##P, u##P, 6, 7), p2##I);
#define G2ROW(I) G2Q(I,0) G2Q(I,1) G2Q(I,2) G2Q(I,3)

// 8-way partial combine for row-group I (rows 64*I+lane), packed (a1,a2)
#define COMB(I) { \
  const int rr = 64 * I + lane; \
  float2 x0 = parts[rr],            x1 = parts[NN + rr]; \
  float2 x2 = parts[2 * NN + rr],   x3 = parts[3 * NN + rr]; \
  float2 x4 = parts[4 * NN + rr],   x5 = parts[5 * NN + rr]; \
  float2 x6 = parts[6 * NN + rr],   x7 = parts[7 * NN + rr]; \
  q1##I = ((x0.x + x1.x) + (x2.x + x3.x)) + ((x4.x + x5.x) + (x6.x + x7.x)); \
  q2##I = ((x0.y + x1.y) + (x2.y + x3.y)) + ((x4.y + x5.y) + (x6.y + x7.y)); }

__global__
__attribute__((amdgpu_flat_work_group_size(512, 512)))
__attribute__((amdgpu_waves_per_eu(2, 2)))
void mvo_kernel(const float* __restrict__ mu,
                const float* __restrict__ U,
                const float* __restrict__ A,
                float* __restrict__ out)
{
  __shared__ alignas(16) float As[16 * NN];      // 16 KB staging (16 rows)
  __shared__ float2 parts[8 * NN];               // 16 KB (a1,a2) partials
  __shared__ alignas(16) float    wsf[NN];       // w fp32
  __shared__ alignas(16) _Float16 whs[NN];       // w fp16 copy
  __shared__ float mus[NN];
  __shared__ float slotA[8];
  __shared__ float slotB[8];
  __shared__ int   doneflag;

  const int t    = threadIdx.x;
  const int b    = blockIdx.x;
  const int lane = t & 63;
  const int wv   = t >> 6;          // col-chunk 0..7 (32 cols each)

  const float* __restrict__ Ub = U + (size_t)b * NN * NN;
  const float* __restrict__ Ab = A + (size_t)b * NN * NN;

  if (t == 0) doneflag = 0;
  if (t < NN) mus[t] = mu[b * NN + t];

  // ---- named register state: 4 rows x 32 cols ----
  float4 c00,c01,c02,c03,c04,c05,c06,c07;
  float4 c10,c11,c12,c13,c14,c15,c16,c17;
  float4 c20,c21,c22,c23,c24,c25,c26,c27;
  float4 c30,c31,c32,c33,c34,c35,c36,c37;
  half2_t g000,g001,g002,g003, g010,g011,g012,g013, g020,g021,g022,g023, g030,g031,g032,g033;
  half2_t g100,g101,g102,g103, g110,g111,g112,g113, g120,g121,g122,g123, g130,g131,g132,g133;
  half2_t g200,g201,g202,g203, g210,g211,g212,g213, g220,g221,g222,g223, g230,g231,g232,g233;
  half2_t g300,g301,g302,g303, g310,g311,g312,g313, g320,g321,g322,g323, g330,g331,g332,g333;
  float fro, d1, d2;

  // ---- Gram phase: A first (-> G2 fp16), then U (-> G1 fp32) ----
  GRAM(Ab);
  d2 = fro;                         // ||A||_F^2 partial
  CVT_ALL()
  GRAM(Ub);
  d1 = fro;                         // ||U||_F^2 partial

  #pragma unroll
  for (int m = 1; m < 64; m <<= 1) {
    d1 += __shfl_xor(d1, m, 64);
    d2 += __shfl_xor(d2, m, 64);
  }
  if (lane == 0) { slotA[wv] = d1; slotB[wv] = d2; }
  if (t < NN) { wsf[t] = 1.0f / 256.0f; whs[t] = (_Float16)(1.0f / 256.0f); }
  __syncthreads();
  float froU2 = 0.f, froA2 = 0.f;
  #pragma unroll
  for (int k = 0; k < 8; ++k) { froU2 += slotA[k]; froA2 += slotB[k]; }
  const float step = 1.0f / (froU2 + KAPPA_F * sqrtf(froA2) + 1.0f);

  // ---------------- PGD iterations (max 400, exact early exit) -------------
  #pragma unroll 1
  for (int it = 0; it < N_ITERS; ++it) {
    // Phase A: register-resident partial matvecs (all 8 waves)
    float p10 = 0.f, p11 = 0.f, p12 = 0.f, p13 = 0.f;
    {
      const float4* wqp = (const float4*)wsf + 8 * wv;   // broadcast reads
      float4 wq0 = wqp[0], wq1 = wqp[1], wq2 = wqp[2], wq3 = wqp[3];
      float4 wq4 = wqp[4], wq5 = wqp[5], wq6 = wqp[6], wq7 = wqp[7];
      G1ROW(0) G1ROW(1) G1ROW(2) G1ROW(3)
    }
    float p20 = 0.f, p21 = 0.f, p22 = 0.f, p23 = 0.f;
    {
      const half8_t* whp = (const half8_t*)whs + 4 * wv; // broadcast reads
      half8_t u0 = whp[0], u1 = whp[1], u2 = whp[2], u3 = whp[3];
      G2ROW(0) G2ROW(1) G2ROW(2) G2ROW(3)
    }
    parts[wv * NN + lane]       = make_float2(p10, p20);
    parts[wv * NN + 64 + lane]  = make_float2(p11, p21);
    parts[wv * NN + 128 + lane] = make_float2(p12, p22);
    parts[wv * NN + 192 + lane] = make_float2(p13, p23);
    __syncthreads();

    // Phase B+C fused on wave 0: combine, grad, candidate, exact projection
    if (wv == 0) {
      float q10, q11, q12, q13, q20, q21, q22, q23;
      COMB(0) COMB(1) COMB(2) COMB(3)
      float w_0 = wsf[lane],       w_1 = wsf[64 + lane];
      float w_2 = wsf[128 + lane], w_3 = wsf[192 + lane];
      float dot = fmaf(q20, w_0, fmaf(q21, w_1, fmaf(q22, w_2, q23 * w_3)));
      #pragma unroll
      for (int m = 1; m < 64; m <<= 1) dot += __shfl_xor(dot, m, 64);
      float nrm = sqrtf(fmaxf(dot, 1e-12f));
      float kon = KAPPA_F / nrm;
      float v0 = w_0 - step * (q10 + kon * q20 - mus[lane]);
      float v1 = w_1 - step * (q11 + kon * q21 - mus[64 + lane]);
      float v2 = w_2 - step * (q12 + kon * q22 - mus[128 + lane]);
      float v3 = w_3 - step * (q13 + kon * q23 - mus[192 + lane]);
      // exact simplex projection (Michelot)
      float s = v0 + v1 + v2 + v3;
      #pragma unroll
      for (int m = 1; m < 64; m <<= 1) s += __shfl_xor(s, m, 64);
      float tau = (s - 1.0f) * (1.0f / 256.0f);
      float cprev = 256.0f;
      for (int ms = 0; ms < 24; ++ms) {
        float s2 = (v0 > tau ? v0 : 0.f) + (v1 > tau ? v1 : 0.f)
                 + (v2 > tau ? v2 : 0.f) + (v3 > tau ? v3 : 0.f);
        float c2 = (v0 > tau ? 1.f : 0.f) + (v1 > tau ? 1.f : 0.f)
                 + (v2 > tau ? 1.f : 0.f) + (v3 > tau ? 1.f : 0.f);
        #pragma unroll
        for (int m = 1; m < 64; m <<= 1) {
          s2 += __shfl_xor(s2, m, 64);
          c2 += __shfl_xor(c2, m, 64);
        }
        if (c2 == cprev) break;   // active set stable -> tau exact (uniform)
        tau = (s2 - 1.0f) / c2;
        cprev = c2;
      }
      float nw0 = fmaxf(v0 - tau, 0.f);
      float nw1 = fmaxf(v1 - tau, 0.f);
      float nw2 = fmaxf(v2 - tau, 0.f);
      float nw3 = fmaxf(v3 - tau, 0.f);
      // bitwise fixed point => all remaining iterations are the identity map
      int same = (nw0 == w_0) && (nw1 == w_1) && (nw2 == w_2) && (nw3 == w_3);
      int conv = __all(same);
      wsf[lane]       = nw0; wsf[64 + lane]  = nw1;
      wsf[128 + lane] = nw2; wsf[192 + lane] = nw3;
      whs[lane]       = (_Float16)nw0; whs[64 + lane]  = (_Float16)nw1;
      whs[128 + lane] = (_Float16)nw2; whs[192 + lane] = (_Float16)nw3;
      if (lane == 0) doneflag = conv;
    }
    __syncthreads();
    if (doneflag) break;
  }

  // Final clamp (already >=0) + renormalize + store
  if (wv == 0) {
    float w_0 = wsf[lane],       w_1 = wsf[64 + lane];
    float w_2 = wsf[128 + lane], w_3 = wsf[192 + lane];
    float s = w_0 + w_1 + w_2 + w_3;
    #pragma unroll
    for (int m = 1; m < 64; m <<= 1) s += __shfl_xor(s, m, 64);
    float inv = 1.0f / (s + 1e-12f);
    float* ob = out + b * NN;
    ob[lane]        = w_0 * inv;
    ob[64 + lane]   = w_1 * inv;
    ob[128 + lane]  = w_2 * inv;
    ob[192 + lane]  = w_3 * inv;
  }
}

extern "C" void kernel_launch(void* const* d_in, const int* in_sizes, int n_in,
                              void* d_out, int out_size, void* d_ws, size_t ws_size,
                              hipStream_t stream) {
  const float* mu = (const float*)d_in[0];
  const float* U  = (const float*)d_in[1];
  const float* A  = (const float*)d_in[2];
  float* out = (float*)d_out;
  hipLaunchKernelGGL(mvo_kernel, dim3(NB), dim3(512), 0, stream, mu, U, A, out);
}

// Round 2
// 2662.234 us; speedup vs baseline: 1.6788x; 1.5732x over previous
//
#include <hip/hip_runtime.h>
#include <math.h>

#define NB 512
#define NN 256
#define N_ITERS 400
#define KAPPA_F 0.1f

typedef _Float16 half2_t __attribute__((ext_vector_type(2)));
typedef _Float16 half8_t __attribute__((ext_vector_type(8)));

__device__ inline float fdot2f(half2_t a, half2_t b, float c) {
#if __has_builtin(__builtin_amdgcn_fdot2)
  return __builtin_amdgcn_fdot2(a, b, c, false);
#else
  return (float)a.x * (float)b.x + (float)a.y * (float)b.y + c;
#endif
}

// R5 redesign driven by R0/R1 evidence: VGPR_Count came back as exactly HALF
// the waves_per_eu budget both times (wpe(4,4)->64, wpe(2,2)->128) with
// ~700-980MB of scratch writes -> the allocator split the unified file
// (arch half + AGPR half) because peak pressure (~240) exceeded the arch
// half, and the overflow spilled to scratch INSIDE the 400-iter loop.
// Rule: peak live set must stay under ~120 regs at 512 threads.
//
// New state budget (512 thr, 8 waves, wpe(2,2)):
//   G1 = U^T U: fp16 OFF-DIAG in registers, 64 half2/thread (4 rows x 32 cols)
//   G2 = A^T A: fp16 OFF-DIAG in LDS (128 KB), XOR-swizzled rows
//   diagonals:  fp32 in LDS (1 KB each), folded back with fp32 w ->
//               fp16 relative error only touches off-diag (~16 magnitude)
//               entries, not the ~256 diagonal => w* shift ~1e-6..1e-5.
// Gram runs as 8 passes (1 row x 32 cols/thread = 32 acc regs) re-staging
// the source matrix each pass; peak live ~112 everywhere.

#define SB() __builtin_amdgcn_sched_barrier(0);
#define PAIR(V, K) __builtin_shufflevector(V, V, 2*(K), 2*(K)+1)

// ---------------- Gram pass: c[A0..A7] = (SRC^T SRC)[RB+lane][32wv..+32)
#define ZA(J) cA##J.x=0.f; cA##J.y=0.f; cA##J.z=0.f; cA##J.w=0.f;
#define GMAC(J, F) { cA##J.x = fmaf(a0, F.x, cA##J.x); cA##J.y = fmaf(a0, F.y, cA##J.y); \
                     cA##J.z = fmaf(a0, F.z, cA##J.z); cA##J.w = fmaf(a0, F.w, cA##J.w); }
#define GRAM1(SRC, RB, DOFRO) do { \
  const float4* __restrict__ src4 = (const float4*)(SRC); \
  ZA(0) ZA(1) ZA(2) ZA(3) ZA(4) ZA(5) ZA(6) ZA(7) \
  float4 st = src4[t]; \
  _Pragma("unroll 1") \
  for (int kt = 0; kt < 32; ++kt) { \
    __syncthreads(); \
    ((float4*)As)[t] = st; \
    if (DOFRO) fro += st.x*st.x + st.y*st.y + st.z*st.z + st.w*st.w; \
    __syncthreads(); \
    if (kt < 31) st = src4[(kt + 1) * 512 + t]; \
    _Pragma("unroll 1") \
    for (int k = 0; k < 8; ++k) { \
      const float* rowp = As + k * NN; \
      float a0 = rowp[(RB) + lane]; \
      const float4* rp4 = (const float4*)(rowp + 32 * wv); \
      { float4 f0=rp4[0], f1=rp4[1], f2=rp4[2], f3=rp4[3]; \
        GMAC(0,f0) GMAC(1,f1) GMAC(2,f2) GMAC(3,f3) } \
      { float4 f0=rp4[4], f1=rp4[5], f2=rp4[6], f3=rp4[7]; \
        GMAC(4,f0) GMAC(5,f1) GMAC(6,f2) GMAC(7,f3) } \
    } \
  } \
} while (0)

// Convert one Gram pass -> 16 named half2 G1 regs, diag -> fp32 LDS, zeroed in fp16
#define CV1(P, GA, GB, J) { \
  float x0=cA##J.x, x1=cA##J.y, x2=cA##J.z, x3=cA##J.w; \
  const int cb = 32*wv + 4*(J); \
  if (cb+0==row_) { diag1[row_]=x0; x0=0.f; } \
  if (cb+1==row_) { diag1[row_]=x1; x1=0.f; } \
  if (cb+2==row_) { diag1[row_]=x2; x2=0.f; } \
  if (cb+3==row_) { diag1[row_]=x3; x3=0.f; } \
  { half2_t h; h.x=(_Float16)x0; h.y=(_Float16)x1; g##P##GA = h; \
    h.x=(_Float16)x2; h.y=(_Float16)x3; g##P##GB = h; } }
#define CVTG1(P, RB) { const int row_ = (RB) + lane; \
  CV1(P,0,1,0) CV1(P,2,3,1) CV1(P,4,5,2) CV1(P,6,7,3) \
  CV1(P,8,9,4) CV1(P,10,11,5) CV1(P,12,13,6) CV1(P,14,15,7) }

// Convert one Gram pass -> swizzled fp16 LDS (G2), diag -> fp32 LDS, zeroed
#define PK2(CJ, CK, M) { \
  float x0=cA##CJ.x, x1=cA##CJ.y, x2=cA##CJ.z, x3=cA##CJ.w; \
  float x4=cA##CK.x, x5=cA##CK.y, x6=cA##CK.z, x7=cA##CK.w; \
  const int cb = 32*wv + 8*(M); \
  if (cb+0==row_) { diag2[row_]=x0; x0=0.f; } \
  if (cb+1==row_) { diag2[row_]=x1; x1=0.f; } \
  if (cb+2==row_) { diag2[row_]=x2; x2=0.f; } \
  if (cb+3==row_) { diag2[row_]=x3; x3=0.f; } \
  if (cb+4==row_) { diag2[row_]=x4; x4=0.f; } \
  if (cb+5==row_) { diag2[row_]=x5; x5=0.f; } \
  if (cb+6==row_) { diag2[row_]=x6; x6=0.f; } \
  if (cb+7==row_) { diag2[row_]=x7; x7=0.f; } \
  half8_t h8; \
  h8[0]=(_Float16)x0; h8[1]=(_Float16)x1; h8[2]=(_Float16)x2; h8[3]=(_Float16)x3; \
  h8[4]=(_Float16)x4; h8[5]=(_Float16)x5; h8[6]=(_Float16)x6; h8[7]=(_Float16)x7; \
  *(half8_t*)((char*)g2s + row_*512 + ((((cb>>3) ^ (row_&31)))<<4)) = h8; }
#define PACKG2(RB) { const int row_ = (RB) + lane; \
  PK2(0,1,0) PK2(2,3,1) PK2(4,5,2) PK2(6,7,3) }

// ---------------- Iteration-loop micro-kernels
#define LH(I, SA, SBo, R) { \
  R##0 = *(const half8_t*)(g2b + (SA) + (I)*32768); \
  R##1 = *(const half8_t*)(g2b + (SBo) + (I)*32768); }

#define D2H(I, R) { \
  p2##I = fdot2f(PAIR(R##0,0), PAIR(uh0,0), p2##I); \
  p2##I = fdot2f(PAIR(R##0,1), PAIR(uh0,1), p2##I); \
  p2##I = fdot2f(PAIR(R##0,2), PAIR(uh0,2), p2##I); \
  p2##I = fdot2f(PAIR(R##0,3), PAIR(uh0,3), p2##I); \
  p2##I = fdot2f(PAIR(R##1,0), PAIR(uh1,0), p2##I); \
  p2##I = fdot2f(PAIR(R##1,1), PAIR(uh1,1), p2##I); \
  p2##I = fdot2f(PAIR(R##1,2), PAIR(uh1,2), p2##I); \
  p2##I = fdot2f(PAIR(R##1,3), PAIR(uh1,3), p2##I); }

#define G1H0(P, I) { \
  p1##I = fdot2f(g##P##0, PAIR(uh0,0), p1##I); \
  p1##I = fdot2f(g##P##1, PAIR(uh0,1), p1##I); \
  p1##I = fdot2f(g##P##2, PAIR(uh0,2), p1##I); \
  p1##I = fdot2f(g##P##3, PAIR(uh0,3), p1##I); \
  p1##I = fdot2f(g##P##4, PAIR(uh1,0), p1##I); \
  p1##I = fdot2f(g##P##5, PAIR(uh1,1), p1##I); \
  p1##I = fdot2f(g##P##6, PAIR(uh1,2), p1##I); \
  p1##I = fdot2f(g##P##7, PAIR(uh1,3), p1##I); }
#define G1H1(P, I) { \
  p1##I = fdot2f(g##P##8,  PAIR(uh0,0), p1##I); \
  p1##I = fdot2f(g##P##9,  PAIR(uh0,1), p1##I); \
  p1##I = fdot2f(g##P##10, PAIR(uh0,2), p1##I); \
  p1##I = fdot2f(g##P##11, PAIR(uh0,3), p1##I); \
  p1##I = fdot2f(g##P##12, PAIR(uh1,0), p1##I); \
  p1##I = fdot2f(g##P##13, PAIR(uh1,1), p1##I); \
  p1##I = fdot2f(g##P##14, PAIR(uh1,2), p1##I); \
  p1##I = fdot2f(g##P##15, PAIR(uh1,3), p1##I); }

// 8-way partial combine (wave0), packed (g1, g2)
#define COMB(I) { \
  const int rr = 64 * (I) + lane; \
  float2 x0 = parts[rr],          x1 = parts[NN + rr]; \
  float2 x2 = parts[2*NN + rr],   x3 = parts[3*NN + rr]; \
  float2 x4 = parts[4*NN + rr],   x5 = parts[5*NN + rr]; \
  float2 x6 = parts[6*NN + rr],   x7 = parts[7*NN + rr]; \
  q1##I = ((x0.x+x1.x)+(x2.x+x3.x))+((x4.x+x5.x)+(x6.x+x7.x)); \
  q2##I = ((x0.y+x1.y)+(x2.y+x3.y))+((x4.y+x5.y)+(x6.y+x7.y)); }

__global__
__attribute__((amdgpu_flat_work_group_size(512, 512)))
__attribute__((amdgpu_waves_per_eu(2, 2)))
void mvo_kernel(const float* __restrict__ mu,
                const float* __restrict__ U,
                const float* __restrict__ A,
                float* __restrict__ out)
{
  __shared__ alignas(16) _Float16 g2s[NN * NN];   // 128 KB, swizzled, diag zeroed
  __shared__ alignas(16) float2 parts[8 * NN];    // 16 KB; first 8 KB doubles as As
  __shared__ alignas(16) float    wsf[NN];        // w fp32
  __shared__ alignas(16) _Float16 whs[NN];        // w fp16
  __shared__ float mus[NN];
  __shared__ float diag1[NN];                     // fp32 diag of U^T U
  __shared__ float diag2[NN];                     // fp32 diag of A^T A
  __shared__ float dslot[8];
  __shared__ float slotA[8];
  __shared__ float slotB[8];
  __shared__ int   doneflag;

  float* As = (float*)parts;                      // 8 x 256 fp32 staging

  const int t    = threadIdx.x;
  const int b    = blockIdx.x;
  const int lane = t & 63;
  const int wv   = t >> 6;          // col-chunk 0..7 (32 cols each)

  const float* __restrict__ Ub = U + (size_t)b * NN * NN;
  const float* __restrict__ Ab = A + (size_t)b * NN * NN;

  if (t == 0) doneflag = 0;
  if (t < NN) mus[t] = mu[b * NN + t];

  // G1 off-diag fp16 state: 4 row-groups x 16 half2 (row 64*I+lane, cols 32wv..+32)
  half2_t gA0,gA1,gA2,gA3,gA4,gA5,gA6,gA7,gA8,gA9,gA10,gA11,gA12,gA13,gA14,gA15;
  half2_t gB0,gB1,gB2,gB3,gB4,gB5,gB6,gB7,gB8,gB9,gB10,gB11,gB12,gB13,gB14,gB15;
  half2_t gC0,gC1,gC2,gC3,gC4,gC5,gC6,gC7,gC8,gC9,gC10,gC11,gC12,gC13,gC14,gC15;
  half2_t gD0,gD1,gD2,gD3,gD4,gD5,gD6,gD7,gD8,gD9,gD10,gD11,gD12,gD13,gD14,gD15;
  float4 cA0, cA1, cA2, cA3, cA4, cA5, cA6, cA7;   // Gram accumulators (32 regs)
  float fro, d1, d2;

  // ---- Gram: G2 (A^T A) -> LDS fp16, 4 passes; then G1 (U^T U) -> regs, 4 passes
  fro = 0.f;
  GRAM1(Ab, 0, 1);   PACKG2(0);
  GRAM1(Ab, 64, 0);  PACKG2(64);
  GRAM1(Ab, 128, 0); PACKG2(128);
  GRAM1(Ab, 192, 0); PACKG2(192);
  d2 = fro;                         // ||A||_F^2 partial
  fro = 0.f;
  GRAM1(Ub, 0, 1);   CVTG1(A, 0);
  GRAM1(Ub, 64, 0);  CVTG1(B, 64);
  GRAM1(Ub, 128, 0); CVTG1(C, 128);
  GRAM1(Ub, 192, 0); CVTG1(D, 192);
  d1 = fro;                         // ||U||_F^2 partial

  #pragma unroll
  for (int m = 1; m < 64; m <<= 1) {
    d1 += __shfl_xor(d1, m, 64);
    d2 += __shfl_xor(d2, m, 64);
  }
  if (lane == 0) { slotA[wv] = d1; slotB[wv] = d2; }
  if (t < NN) { wsf[t] = 1.0f / 256.0f; whs[t] = (_Float16)(1.0f / 256.0f); }
  __syncthreads();
  float froU2 = 0.f, froA2 = 0.f;
  #pragma unroll
  for (int k = 0; k < 8; ++k) { froU2 += slotA[k]; froA2 += slotB[k]; }
  const float step = 1.0f / (froU2 + KAPPA_F * sqrtf(froA2) + 1.0f);

  // loop-invariant addressing for swizzled G2 reads
  const char* g2b = (const char*)g2s + lane * 512;
  const int l31 = lane & 31;
  const int sc0 = ((4*wv + 0) ^ l31) << 4;
  const int sc1 = ((4*wv + 1) ^ l31) << 4;
  const int sc2 = ((4*wv + 2) ^ l31) << 4;
  const int sc3 = ((4*wv + 3) ^ l31) << 4;
  const half8_t* whp = (const half8_t*)whs + 4 * wv;
  const int dsel = lane >> 5;

  // ---------------- PGD iterations ----------------
  #pragma unroll 1
  for (int it = 0; it < N_ITERS; ++it) {
    float p10=0.f, p11=0.f, p12=0.f, p13=0.f;
    float p20=0.f, p21=0.f, p22=0.f, p23=0.f;
    { // columns [32wv, 32wv+16)
      half8_t uh0 = whp[0], uh1 = whp[1];
      half8_t A0, A1, B0, B1;
      LH(0, sc0, sc1, A)
      LH(1, sc0, sc1, B)
      G1H0(A, 0) G1H0(B, 1) G1H0(C, 2) G1H0(D, 3)
      D2H(0, A) SB() LH(2, sc0, sc1, A)
      D2H(1, B) SB() LH(3, sc0, sc1, B)
      D2H(2, A) SB()
      D2H(3, B) SB()
    }
    { // columns [32wv+16, 32wv+32)
      half8_t uh0 = whp[2], uh1 = whp[3];
      half8_t A0, A1, B0, B1;
      LH(0, sc2, sc3, A)
      LH(1, sc2, sc3, B)
      G1H1(A, 0) G1H1(B, 1) G1H1(C, 2) G1H1(D, 3)
      D2H(0, A) SB() LH(2, sc2, sc3, A)
      D2H(1, B) SB() LH(3, sc2, sc3, B)
      D2H(2, A) SB()
      D2H(3, B) SB()
    }
    // fold fp32 diagonals back (exact diag term, fp32 w)
    float w_r0 = wsf[lane],       w_r1 = wsf[64 + lane];
    float w_r2 = wsf[128 + lane], w_r3 = wsf[192 + lane];
    if (wv == dsel)     { p10 = fmaf(diag1[lane],     w_r0, p10);
                          p20 = fmaf(diag2[lane],     w_r0, p20); }
    if (wv == 2 + dsel) { p11 = fmaf(diag1[64+lane],  w_r1, p11);
                          p21 = fmaf(diag2[64+lane],  w_r1, p21); }
    if (wv == 4 + dsel) { p12 = fmaf(diag1[128+lane], w_r2, p12);
                          p22 = fmaf(diag2[128+lane], w_r2, p22); }
    if (wv == 6 + dsel) { p13 = fmaf(diag1[192+lane], w_r3, p13);
                          p23 = fmaf(diag2[192+lane], w_r3, p23); }
    // dot(w, G2 w) partial folded into phase A (hides shfl chain)
    float dpart = fmaf(p20, w_r0, fmaf(p21, w_r1, fmaf(p22, w_r2, p23 * w_r3)));
    #pragma unroll
    for (int m = 1; m < 64; m <<= 1) dpart += __shfl_xor(dpart, m, 64);
    parts[wv * NN + lane]       = make_float2(p10, p20);
    parts[wv * NN + 64 + lane]  = make_float2(p11, p21);
    parts[wv * NN + 128 + lane] = make_float2(p12, p22);
    parts[wv * NN + 192 + lane] = make_float2(p13, p23);
    if (lane == 0) dslot[wv] = dpart;
    __syncthreads();

    // Phase B: combine + grad + exact simplex projection, wave 0 only
    if (wv == 0) {
      float q10, q11, q12, q13, q20, q21, q22, q23;
      COMB(0) COMB(1) COMB(2) COMB(3)
      float dot = ((dslot[0]+dslot[1])+(dslot[2]+dslot[3]))
                + ((dslot[4]+dslot[5])+(dslot[6]+dslot[7]));
      float nrm = sqrtf(fmaxf(dot, 1e-12f));
      float kon = KAPPA_F / nrm;
      float v0 = w_r0 - step * (q10 + kon * q20 - mus[lane]);
      float v1 = w_r1 - step * (q11 + kon * q21 - mus[64 + lane]);
      float v2 = w_r2 - step * (q12 + kon * q22 - mus[128 + lane]);
      float v3 = w_r3 - step * (q13 + kon * q23 - mus[192 + lane]);
      // exact simplex projection (Michelot active-set)
      float s = v0 + v1 + v2 + v3;
      #pragma unroll
      for (int m = 1; m < 64; m <<= 1) s += __shfl_xor(s, m, 64);
      float tau = (s - 1.0f) * (1.0f / 256.0f);
      float cprev = 256.0f;
      for (int ms = 0; ms < 24; ++ms) {
        float s2 = (v0 > tau ? v0 : 0.f) + (v1 > tau ? v1 : 0.f)
                 + (v2 > tau ? v2 : 0.f) + (v3 > tau ? v3 : 0.f);
        float c2 = (v0 > tau ? 1.f : 0.f) + (v1 > tau ? 1.f : 0.f)
                 + (v2 > tau ? 1.f : 0.f) + (v3 > tau ? 1.f : 0.f);
        #pragma unroll
        for (int m = 1; m < 64; m <<= 1) {
          s2 += __shfl_xor(s2, m, 64);
          c2 += __shfl_xor(c2, m, 64);
        }
        if (c2 == cprev) break;   // active set stable -> tau exact (uniform)
        tau = (s2 - 1.0f) / c2;
        cprev = c2;
      }
      float nw0 = fmaxf(v0 - tau, 0.f);
      float nw1 = fmaxf(v1 - tau, 0.f);
      float nw2 = fmaxf(v2 - tau, 0.f);
      float nw3 = fmaxf(v3 - tau, 0.f);
      int same = (nw0 == w_r0) && (nw1 == w_r1) && (nw2 == w_r2) && (nw3 == w_r3);
      int conv = __all(same);     // bitwise fixed point -> rest are identity
      wsf[lane]       = nw0; wsf[64 + lane]  = nw1;
      wsf[128 + lane] = nw2; wsf[192 + lane] = nw3;
      whs[lane]       = (_Float16)nw0; whs[64 + lane]  = (_Float16)nw1;
      whs[128 + lane] = (_Float16)nw2; whs[192 + lane] = (_Float16)nw3;
      if (lane == 0) doneflag = conv;
    }
    __syncthreads();
    if (doneflag) break;
  }

  // Final clamp (already >=0) + renormalize + store
  if (wv == 0) {
    float w_0 = wsf[lane],       w_1 = wsf[64 + lane];
    float w_2 = wsf[128 + lane], w_3 = wsf[192 + lane];
    float s = w_0 + w_1 + w_2 + w_3;
    #pragma unroll
    for (int m = 1; m < 64; m <<= 1) s += __shfl_xor(s, m, 64);
    float inv = 1.0f / (s + 1e-12f);
    float* ob = out + b * NN;
    ob[lane]        = w_0 * inv;
    ob[64 + lane]   = w_1 * inv;
    ob[128 + lane]  = w_2 * inv;
    ob[192 + lane]  = w_3 * inv;
  }
}

extern "C" void kernel_launch(void* const* d_in, const int* in_sizes, int n_in,
                              void* d_out, int out_size, void* d_ws, size_t ws_size,
                              hipStream_t stream) {
  const float* mu = (const float*)d_in[0];
  const float* U  = (const float*)d_in[1];
  const float* A  = (const float*)d_in[2];
  float* out = (float*)d_out;
  hipLaunchKernelGGL(mvo_kernel, dim3(NB), dim3(512), 0, stream, mu, U, A, out);
}

// Round 3
// 2419.029 us; speedup vs baseline: 1.8476x; 1.1005x over previous
//
#include <hip/hip_runtime.h>
#include <math.h>

#define NB 512
#define NN 256
#define N_ITERS 400
#define KAPPA_F 0.1f

typedef _Float16 half2_t __attribute__((ext_vector_type(2)));
typedef _Float16 half8_t __attribute__((ext_vector_type(8)));

__device__ inline float fdot2f(half2_t a, half2_t b, float c) {
#if __has_builtin(__builtin_amdgcn_fdot2)
  return __builtin_amdgcn_fdot2(a, b, c, false);
#else
  return (float)a.x * (float)b.x + (float)a.y * (float)b.y + c;
#endif
}

// R3: both Gram matrices fully register-resident as fp16 off-diag.
// Evidence chain: R0/R1 showed peak-live > budget => allocator split + ~1GB
// scratch. R2 (G2 in LDS) came back VGPR=96 of a 256 budget, WRITE=0.5MB,
// 0 bank conflicts -> 160 idle registers while phase A paid 16 ds_read_b128
// per thread per iteration (~131KB/iter/CU) plus sched_barrier pins that
// serialized load->use chains. Fix: G1 = 16 half8 regs (64 VGPR), G2 = 16
// half8 regs (64 VGPR); diagonals exact fp32 in LDS (folded with fp32 w);
// phase A is pure-register v_dot2_f32_f16 (128/iter). Peak live ~190 < 256.
// Accumulation order kept bitwise-identical to R2.
// LDS drops 149KB -> ~21KB (still 1 block/CU: 2 blocks would need <=128
// VGPR/thread which is exactly the R1 spill regime).

#define PAIR(V, K) __builtin_shufflevector(V, V, 2*(K), 2*(K)+1)

#define DOT8(ACC, R, UH) \
  ACC = fdot2f(PAIR(R,0), PAIR(UH,0), ACC); \
  ACC = fdot2f(PAIR(R,1), PAIR(UH,1), ACC); \
  ACC = fdot2f(PAIR(R,2), PAIR(UH,2), ACC); \
  ACC = fdot2f(PAIR(R,3), PAIR(UH,3), ACC);

// ---------------- Gram pass: two row-groups (RB+lane, RB+64+lane) x 32 cols
#define ZC(P,J) c##P##J.x=0.f; c##P##J.y=0.f; c##P##J.z=0.f; c##P##J.w=0.f;
#define ZALL() ZC(A,0) ZC(A,1) ZC(A,2) ZC(A,3) ZC(A,4) ZC(A,5) ZC(A,6) ZC(A,7) \
               ZC(B,0) ZC(B,1) ZC(B,2) ZC(B,3) ZC(B,4) ZC(B,5) ZC(B,6) ZC(B,7)

#define GMA(J,F) { cA##J.x=fmaf(a0,F.x,cA##J.x); cA##J.y=fmaf(a0,F.y,cA##J.y); \
                   cA##J.z=fmaf(a0,F.z,cA##J.z); cA##J.w=fmaf(a0,F.w,cA##J.w); }
#define GMB(J,F) { cB##J.x=fmaf(a1,F.x,cB##J.x); cB##J.y=fmaf(a1,F.y,cB##J.y); \
                   cB##J.z=fmaf(a1,F.z,cB##J.z); cB##J.w=fmaf(a1,F.w,cB##J.w); }

#define GRAM2(SRC, RB, DOFRO) do { \
  const float4* __restrict__ src4 = (const float4*)(SRC); \
  ZALL() \
  float4 st0 = src4[t], st1 = src4[512 + t]; \
  _Pragma("unroll 1") \
  for (int kt = 0; kt < 16; ++kt) { \
    __syncthreads(); \
    ((float4*)As)[t] = st0; \
    ((float4*)As)[512 + t] = st1; \
    if (DOFRO) { fro += st0.x*st0.x + st0.y*st0.y + st0.z*st0.z + st0.w*st0.w; \
                 fro += st1.x*st1.x + st1.y*st1.y + st1.z*st1.z + st1.w*st1.w; } \
    __syncthreads(); \
    if (kt < 15) { st0 = src4[(kt+1)*1024 + t]; st1 = src4[(kt+1)*1024 + 512 + t]; } \
    _Pragma("unroll 1") \
    for (int k = 0; k < 16; ++k) { \
      const float* rowp = As + k * NN; \
      float a0 = rowp[(RB) + lane]; \
      float a1 = rowp[(RB) + 64 + lane]; \
      const float4* rp4 = (const float4*)(rowp + 32 * wv); \
      { float4 f0=rp4[0], f1=rp4[1], f2=rp4[2], f3=rp4[3]; \
        GMA(0,f0) GMA(1,f1) GMA(2,f2) GMA(3,f3) \
        GMB(0,f0) GMB(1,f1) GMB(2,f2) GMB(3,f3) } \
      { float4 f4=rp4[4], f5=rp4[5], f6=rp4[6], f7=rp4[7]; \
        GMA(4,f4) GMA(5,f5) GMA(6,f6) GMA(7,f7) \
        GMB(4,f4) GMB(5,f5) GMB(6,f6) GMB(7,f7) } \
    } \
  } \
} while (0)

// Pack one col-oct of one row-group: diag -> fp32 LDS (zeroed in fp16), rest half8
#define PACK8(RREG, M, DIAG, FA, FB) { \
  float x0=FA.x, x1=FA.y, x2=FA.z, x3=FA.w; \
  float x4=FB.x, x5=FB.y, x6=FB.z, x7=FB.w; \
  const int cb = 32*wv + 8*(M); \
  if (cb+0==row_) { DIAG[row_]=x0; x0=0.f; } \
  if (cb+1==row_) { DIAG[row_]=x1; x1=0.f; } \
  if (cb+2==row_) { DIAG[row_]=x2; x2=0.f; } \
  if (cb+3==row_) { DIAG[row_]=x3; x3=0.f; } \
  if (cb+4==row_) { DIAG[row_]=x4; x4=0.f; } \
  if (cb+5==row_) { DIAG[row_]=x5; x5=0.f; } \
  if (cb+6==row_) { DIAG[row_]=x6; x6=0.f; } \
  if (cb+7==row_) { DIAG[row_]=x7; x7=0.f; } \
  half8_t h8; \
  h8[0]=(_Float16)x0; h8[1]=(_Float16)x1; h8[2]=(_Float16)x2; h8[3]=(_Float16)x3; \
  h8[4]=(_Float16)x4; h8[5]=(_Float16)x5; h8[6]=(_Float16)x6; h8[7]=(_Float16)x7; \
  RREG = h8; }

#define PACKG(PFX, CP, DIAG, RB) { const int row_ = (RB) + lane; \
  PACK8(PFX##0, 0, DIAG, c##CP##0, c##CP##1) \
  PACK8(PFX##1, 1, DIAG, c##CP##2, c##CP##3) \
  PACK8(PFX##2, 2, DIAG, c##CP##4, c##CP##5) \
  PACK8(PFX##3, 3, DIAG, c##CP##6, c##CP##7) }

// 8-way partial combine (wave0), packed (g1, g2)
#define COMB(I) { \
  const int rr = 64 * (I) + lane; \
  float2 x0 = parts[rr],          x1 = parts[NN + rr]; \
  float2 x2 = parts[2*NN + rr],   x3 = parts[3*NN + rr]; \
  float2 x4 = parts[4*NN + rr],   x5 = parts[5*NN + rr]; \
  float2 x6 = parts[6*NN + rr],   x7 = parts[7*NN + rr]; \
  q1##I = ((x0.x+x1.x)+(x2.x+x3.x))+((x4.x+x5.x)+(x6.x+x7.x)); \
  q2##I = ((x0.y+x1.y)+(x2.y+x3.y))+((x4.y+x5.y)+(x6.y+x7.y)); }

__global__
__attribute__((amdgpu_flat_work_group_size(512, 512)))
__attribute__((amdgpu_waves_per_eu(2, 2)))
void mvo_kernel(const float* __restrict__ mu,
                const float* __restrict__ U,
                const float* __restrict__ A,
                float* __restrict__ out)
{
  __shared__ alignas(16) float2 parts[8 * NN];    // 16 KB; doubles as As staging
  __shared__ alignas(16) float    wsf[NN];        // w fp32
  __shared__ alignas(16) _Float16 whs[NN];        // w fp16
  __shared__ float mus[NN];
  __shared__ float diag1[NN];                     // fp32 diag of U^T U
  __shared__ float diag2[NN];                     // fp32 diag of A^T A
  __shared__ float dslot[8];
  __shared__ float slotA[8];
  __shared__ float slotB[8];
  __shared__ int   doneflag;

  float* As = (float*)parts;                      // 16 rows x 256 fp32 staging

  const int t    = threadIdx.x;
  const int b    = blockIdx.x;
  const int lane = t & 63;
  const int wv   = t >> 6;          // col-chunk 0..7 (32 cols each)

  const float* __restrict__ Ub = U + (size_t)b * NN * NN;
  const float* __restrict__ Ab = A + (size_t)b * NN * NN;

  if (t == 0) doneflag = 0;
  if (t < NN) mus[t] = mu[b * NN + t];

  // Register state: G1 (U^TU) = e[A-D][0-3], G2 (A^TA) = h[A-D][0-3]
  // Row-group I covers row 64*I+lane, cols [32wv, 32wv+32) as 4 half8 octs.
  half8_t eA0,eA1,eA2,eA3, eB0,eB1,eB2,eB3, eC0,eC1,eC2,eC3, eD0,eD1,eD2,eD3;
  half8_t hA0,hA1,hA2,hA3, hB0,hB1,hB2,hB3, hC0,hC1,hC2,hC3, hD0,hD1,hD2,hD3;
  float4 cA0,cA1,cA2,cA3,cA4,cA5,cA6,cA7;        // Gram accumulators (2x32)
  float4 cB0,cB1,cB2,cB3,cB4,cB5,cB6,cB7;
  float fro, d1, d2;

  // ---- Gram: A^T A -> h regs (2 passes), U^T U -> e regs (2 passes) ----
  fro = 0.f;
  GRAM2(Ab, 0, 1);
  PACKG(hA, A, diag2, 0) PACKG(hB, B, diag2, 64)
  GRAM2(Ab, 128, 0);
  PACKG(hC, A, diag2, 128) PACKG(hD, B, diag2, 192)
  d2 = fro;                          // ||A||_F^2 partial
  fro = 0.f;
  GRAM2(Ub, 0, 1);
  PACKG(eA, A, diag1, 0) PACKG(eB, B, diag1, 64)
  GRAM2(Ub, 128, 0);
  PACKG(eC, A, diag1, 128) PACKG(eD, B, diag1, 192)
  d1 = fro;                          // ||U||_F^2 partial

  #pragma unroll
  for (int m = 1; m < 64; m <<= 1) {
    d1 += __shfl_xor(d1, m, 64);
    d2 += __shfl_xor(d2, m, 64);
  }
  if (lane == 0) { slotA[wv] = d1; slotB[wv] = d2; }
  if (t < NN) { wsf[t] = 1.0f / 256.0f; whs[t] = (_Float16)(1.0f / 256.0f); }
  __syncthreads();
  float froU2 = 0.f, froA2 = 0.f;
  #pragma unroll
  for (int k = 0; k < 8; ++k) { froU2 += slotA[k]; froA2 += slotB[k]; }
  const float step = 1.0f / (froU2 + KAPPA_F * sqrtf(froA2) + 1.0f);

  const half8_t* whp = (const half8_t*)whs + 4 * wv;   // broadcast reads
  const int dsel = lane >> 5;

  // ---------------- PGD iterations (max 400, exact early exit) ------------
  #pragma unroll 1
  for (int it = 0; it < N_ITERS; ++it) {
    // Phase A: pure-register matvecs (128 v_dot2_f32_f16 / thread)
    half8_t uh0 = whp[0], uh1 = whp[1], uh2 = whp[2], uh3 = whp[3];
    float p10=0.f, p11=0.f, p12=0.f, p13=0.f;
    float p20=0.f, p21=0.f, p22=0.f, p23=0.f;
    DOT8(p10, eA0, uh0) DOT8(p10, eA1, uh1) DOT8(p10, eA2, uh2) DOT8(p10, eA3, uh3)
    DOT8(p11, eB0, uh0) DOT8(p11, eB1, uh1) DOT8(p11, eB2, uh2) DOT8(p11, eB3, uh3)
    DOT8(p12, eC0, uh0) DOT8(p12, eC1, uh1) DOT8(p12, eC2, uh2) DOT8(p12, eC3, uh3)
    DOT8(p13, eD0, uh0) DOT8(p13, eD1, uh1) DOT8(p13, eD2, uh2) DOT8(p13, eD3, uh3)
    DOT8(p20, hA0, uh0) DOT8(p20, hA1, uh1) DOT8(p20, hA2, uh2) DOT8(p20, hA3, uh3)
    DOT8(p21, hB0, uh0) DOT8(p21, hB1, uh1) DOT8(p21, hB2, uh2) DOT8(p21, hB3, uh3)
    DOT8(p22, hC0, uh0) DOT8(p22, hC1, uh1) DOT8(p22, hC2, uh2) DOT8(p22, hC3, uh3)
    DOT8(p23, hD0, uh0) DOT8(p23, hD1, uh1) DOT8(p23, hD2, uh2) DOT8(p23, hD3, uh3)

    // exact fp32 diagonal fold (each diag element exactly once across waves)
    float w_r0 = wsf[lane],       w_r1 = wsf[64 + lane];
    float w_r2 = wsf[128 + lane], w_r3 = wsf[192 + lane];
    if (wv == dsel)     { p10 = fmaf(diag1[lane],     w_r0, p10);
                          p20 = fmaf(diag2[lane],     w_r0, p20); }
    if (wv == 2 + dsel) { p11 = fmaf(diag1[64+lane],  w_r1, p11);
                          p21 = fmaf(diag2[64+lane],  w_r1, p21); }
    if (wv == 4 + dsel) { p12 = fmaf(diag1[128+lane], w_r2, p12);
                          p22 = fmaf(diag2[128+lane], w_r2, p22); }
    if (wv == 6 + dsel) { p13 = fmaf(diag1[192+lane], w_r3, p13);
                          p23 = fmaf(diag2[192+lane], w_r3, p23); }
    // dot(w, G2 w) partial folded into phase A
    float dpart = fmaf(p20, w_r0, fmaf(p21, w_r1, fmaf(p22, w_r2, p23 * w_r3)));
    #pragma unroll
    for (int m = 1; m < 64; m <<= 1) dpart += __shfl_xor(dpart, m, 64);
    parts[wv * NN + lane]       = make_float2(p10, p20);
    parts[wv * NN + 64 + lane]  = make_float2(p11, p21);
    parts[wv * NN + 128 + lane] = make_float2(p12, p22);
    parts[wv * NN + 192 + lane] = make_float2(p13, p23);
    if (lane == 0) dslot[wv] = dpart;
    __syncthreads();

    // Phase B: combine + grad + exact simplex projection, wave 0 only
    if (wv == 0) {
      float q10, q11, q12, q13, q20, q21, q22, q23;
      COMB(0) COMB(1) COMB(2) COMB(3)
      float dot = ((dslot[0]+dslot[1])+(dslot[2]+dslot[3]))
                + ((dslot[4]+dslot[5])+(dslot[6]+dslot[7]));
      float nrm = sqrtf(fmaxf(dot, 1e-12f));
      float kon = KAPPA_F / nrm;
      float v0 = w_r0 - step * (q10 + kon * q20 - mus[lane]);
      float v1 = w_r1 - step * (q11 + kon * q21 - mus[64 + lane]);
      float v2 = w_r2 - step * (q12 + kon * q22 - mus[128 + lane]);
      float v3 = w_r3 - step * (q13 + kon * q23 - mus[192 + lane]);
      // exact simplex projection (Michelot active-set, cold start: monotone)
      float s = v0 + v1 + v2 + v3;
      #pragma unroll
      for (int m = 1; m < 64; m <<= 1) s += __shfl_xor(s, m, 64);
      float tau = (s - 1.0f) * (1.0f / 256.0f);
      float cprev = 256.0f;
      for (int ms = 0; ms < 24; ++ms) {
        float s2 = (v0 > tau ? v0 : 0.f) + (v1 > tau ? v1 : 0.f)
                 + (v2 > tau ? v2 : 0.f) + (v3 > tau ? v3 : 0.f);
        float c2 = (v0 > tau ? 1.f : 0.f) + (v1 > tau ? 1.f : 0.f)
                 + (v2 > tau ? 1.f : 0.f) + (v3 > tau ? 1.f : 0.f);
        #pragma unroll
        for (int m = 1; m < 64; m <<= 1) {
          s2 += __shfl_xor(s2, m, 64);
          c2 += __shfl_xor(c2, m, 64);
        }
        if (c2 == cprev) break;   // active set stable -> tau exact (uniform)
        tau = (s2 - 1.0f) / c2;
        cprev = c2;
      }
      float nw0 = fmaxf(v0 - tau, 0.f);
      float nw1 = fmaxf(v1 - tau, 0.f);
      float nw2 = fmaxf(v2 - tau, 0.f);
      float nw3 = fmaxf(v3 - tau, 0.f);
      int same = (nw0 == w_r0) && (nw1 == w_r1) && (nw2 == w_r2) && (nw3 == w_r3);
      int conv = __all(same);     // bitwise fixed point -> rest are identity
      wsf[lane]       = nw0; wsf[64 + lane]  = nw1;
      wsf[128 + lane] = nw2; wsf[192 + lane] = nw3;
      whs[lane]       = (_Float16)nw0; whs[64 + lane]  = (_Float16)nw1;
      whs[128 + lane] = (_Float16)nw2; whs[192 + lane] = (_Float16)nw3;
      if (lane == 0) doneflag = conv;
    }
    __syncthreads();
    if (doneflag) break;
  }

  // Final clamp (already >=0) + renormalize + store
  if (wv == 0) {
    float w_0 = wsf[lane],       w_1 = wsf[64 + lane];
    float w_2 = wsf[128 + lane], w_3 = wsf[192 + lane];
    float s = w_0 + w_1 + w_2 + w_3;
    #pragma unroll
    for (int m = 1; m < 64; m <<= 1) s += __shfl_xor(s, m, 64);
    float inv = 1.0f / (s + 1e-12f);
    float* ob = out + b * NN;
    ob[lane]        = w_0 * inv;
    ob[64 + lane]   = w_1 * inv;
    ob[128 + lane]  = w_2 * inv;
    ob[192 + lane]  = w_3 * inv;
  }
}

extern "C" void kernel_launch(void* const* d_in, const int* in_sizes, int n_in,
                              void* d_out, int out_size, void* d_ws, size_t ws_size,
                              hipStream_t stream) {
  const float* mu = (const float*)d_in[0];
  const float* U  = (const float*)d_in[1];
  const float* A  = (const float*)d_in[2];
  float* out = (float*)d_out;
  hipLaunchKernelGGL(mvo_kernel, dim3(NB), dim3(512), 0, stream, mu, U, A, out);
}

// Round 4
// 2132.896 us; speedup vs baseline: 2.0954x; 1.1342x over previous
//
#include <hip/hip_runtime.h>
#include <math.h>

#define NB 512
#define NN 256
#define N_ITERS 400
#define KAPPA_F 0.1f

typedef _Float16 half2_t __attribute__((ext_vector_type(2)));
typedef _Float16 half8_t __attribute__((ext_vector_type(8)));

__device__ inline float fdot2f(half2_t a, half2_t b, float c) {
#if __has_builtin(__builtin_amdgcn_fdot2)
  return __builtin_amdgcn_fdot2(a, b, c, false);
#else
  return (float)a.x * (float)b.x + (float)a.y * (float)b.y + c;
#endif
}

// R4. Evidence chain:
//  R0/R1: peak-live > arch budget -> allocator split + ~1GB loop scratch.
//  R2:    G2 in LDS, 96 VGPR clean, 0.5MB writes -> pressure model works.
//  R3:    G in 32 half8 QUADS (128 VGPR, tuple-aligned) + Gram peak ~200 at
//         wpe(2,2) -> allocator split AGAIN (VGPR=128, 96MB scratch) and
//         loop G lives partly in AGPRs -> v_accvgpr moves per dot -> only -9%.
// Fixes:
//  (a) G as 128 LOOSE half2 names (1 VGPR each, no tuple constraints);
//      U-Gram as 4 single-row-group passes (32-reg accumulator) to cap peak
//      live ~175; waves_per_eu(1,2) -> budget 512, allocator should pick
//      ~180-200 clean (still 2 waves/SIMD at <=256).
//  (b) Warm-start Michelot with previous iteration's tau (stored in LDS).
//      EXACT: break requires stable count; nested threshold sets of equal
//      size are equal; a self-consistent threshold set satisfies KKT ->
//      unique tau*. tau=-1e30 at iter 0 == cold start bit-for-bit.
//  (c) DPP-based 64-lane reductions (quad_perm xor1/xor2, row_half_mirror,
//      row_mirror, then shfl_xor 16/32) for dpart + Michelot dual-reduce.
//      d1/d2/step keep the old shfl path so step stays bitwise-stable.

#define PAIR(V, K) __builtin_shufflevector(V, V, 2*(K), 2*(K)+1)

template <int CTRL>
__device__ inline float dpp_addt(float v) {
  int s = __builtin_amdgcn_update_dpp(0, __float_as_int(v), CTRL, 0xF, 0xF, true);
  return v + __int_as_float(s);
}
__device__ inline float wave_sum(float v) {
  v = dpp_addt<0xB1>(v);    // quad_perm [1,0,3,2]  (xor1)
  v = dpp_addt<0x4E>(v);    // quad_perm [2,3,0,1]  (xor2)
  v = dpp_addt<0x141>(v);   // row_half_mirror      (xor4-equiv after above)
  v = dpp_addt<0x140>(v);   // row_mirror           (xor8-equiv)
  v += __shfl_xor(v, 16, 64);
  v += __shfl_xor(v, 32, 64);
  return v;
}
__device__ inline void wave_sum2(float& a, float& b) {
  a = dpp_addt<0xB1>(a);  b = dpp_addt<0xB1>(b);
  a = dpp_addt<0x4E>(a);  b = dpp_addt<0x4E>(b);
  a = dpp_addt<0x141>(a); b = dpp_addt<0x141>(b);
  a = dpp_addt<0x140>(a); b = dpp_addt<0x140>(b);
  a += __shfl_xor(a, 16, 64); b += __shfl_xor(b, 16, 64);
  a += __shfl_xor(a, 32, 64); b += __shfl_xor(b, 32, 64);
}

// ---- loose half2 G register names: P in {e0_,e1_,e2_,e3_,h0_,h1_,h2_,h3_}
#define DECLROW(P) half2_t P##0,P##1,P##2,P##3,P##4,P##5,P##6,P##7, \
                           P##8,P##9,P##10,P##11,P##12,P##13,P##14,P##15;

// ---- Gram accumulators / MACs
#define ZA(J) cA##J.x=0.f; cA##J.y=0.f; cA##J.z=0.f; cA##J.w=0.f;
#define ZB(J) cB##J.x=0.f; cB##J.y=0.f; cB##J.z=0.f; cB##J.w=0.f;
#define ZALL() ZA(0) ZA(1) ZA(2) ZA(3) ZA(4) ZA(5) ZA(6) ZA(7) \
               ZB(0) ZB(1) ZB(2) ZB(3) ZB(4) ZB(5) ZB(6) ZB(7)
#define GMA(J,F) { cA##J.x=fmaf(a0,F.x,cA##J.x); cA##J.y=fmaf(a0,F.y,cA##J.y); \
                   cA##J.z=fmaf(a0,F.z,cA##J.z); cA##J.w=fmaf(a0,F.w,cA##J.w); }
#define GMB(J,F) { cB##J.x=fmaf(a1,F.x,cB##J.x); cB##J.y=fmaf(a1,F.y,cB##J.y); \
                   cB##J.z=fmaf(a1,F.z,cB##J.z); cB##J.w=fmaf(a1,F.w,cB##J.w); }

// Two-row-group Gram pass (rows RB+lane, RB+64+lane) — used for A (low pressure)
#define GRAM2(SRC, RB, DOFRO) do { \
  const float4* __restrict__ src4 = (const float4*)(SRC); \
  ZALL() \
  float4 st0 = src4[t], st1 = src4[512 + t]; \
  _Pragma("unroll 1") \
  for (int kt = 0; kt < 16; ++kt) { \
    __syncthreads(); \
    ((float4*)As)[t] = st0; \
    ((float4*)As)[512 + t] = st1; \
    if (DOFRO) { fro += st0.x*st0.x + st0.y*st0.y + st0.z*st0.z + st0.w*st0.w; \
                 fro += st1.x*st1.x + st1.y*st1.y + st1.z*st1.z + st1.w*st1.w; } \
    __syncthreads(); \
    if (kt < 15) { st0 = src4[(kt+1)*1024 + t]; st1 = src4[(kt+1)*1024 + 512 + t]; } \
    _Pragma("unroll 1") \
    for (int k = 0; k < 16; ++k) { \
      const float* rowp = As + k * NN; \
      float a0 = rowp[(RB) + lane]; \
      float a1 = rowp[(RB) + 64 + lane]; \
      const float4* rp4 = (const float4*)(rowp + 32 * wv); \
      { float4 f0=rp4[0], f1=rp4[1], f2=rp4[2], f3=rp4[3]; \
        GMA(0,f0) GMA(1,f1) GMA(2,f2) GMA(3,f3) \
        GMB(0,f0) GMB(1,f1) GMB(2,f2) GMB(3,f3) } \
      { float4 f4=rp4[4], f5=rp4[5], f6=rp4[6], f7=rp4[7]; \
        GMA(4,f4) GMA(5,f5) GMA(6,f6) GMA(7,f7) \
        GMB(4,f4) GMB(5,f5) GMB(6,f6) GMB(7,f7) } \
    } \
  } \
} while (0)

// Single-row-group Gram pass (row RB+lane) — used for U (caps peak pressure)
#define GRAM1(SRC, RB, DOFRO) do { \
  const float4* __restrict__ src4 = (const float4*)(SRC); \
  ZA(0) ZA(1) ZA(2) ZA(3) ZA(4) ZA(5) ZA(6) ZA(7) \
  float4 st = src4[t]; \
  _Pragma("unroll 1") \
  for (int kt = 0; kt < 32; ++kt) { \
    __syncthreads(); \
    ((float4*)As)[t] = st; \
    if (DOFRO) fro += st.x*st.x + st.y*st.y + st.z*st.z + st.w*st.w; \
    __syncthreads(); \
    if (kt < 31) st = src4[(kt + 1) * 512 + t]; \
    _Pragma("unroll 1") \
    for (int k = 0; k < 8; ++k) { \
      const float* rowp = As + k * NN; \
      float a0 = rowp[(RB) + lane]; \
      const float4* rp4 = (const float4*)(rowp + 32 * wv); \
      { float4 f0=rp4[0], f1=rp4[1], f2=rp4[2], f3=rp4[3]; \
        GMA(0,f0) GMA(1,f1) GMA(2,f2) GMA(3,f3) } \
      { float4 f4=rp4[4], f5=rp4[5], f6=rp4[6], f7=rp4[7]; \
        GMA(4,f4) GMA(5,f5) GMA(6,f6) GMA(7,f7) } \
    } \
  } \
} while (0)

// Pack one float4 (4 cols) -> 2 loose half2; diag -> fp32 LDS, zeroed in fp16
#define PACK4(PA, PB, C, J4, DIAG) { \
  float x0=C.x, x1=C.y, x2=C.z, x3=C.w; \
  const int cb = 32*wv + 4*(J4); \
  if (cb+0==row_) { DIAG[row_]=x0; x0=0.f; } \
  if (cb+1==row_) { DIAG[row_]=x1; x1=0.f; } \
  if (cb+2==row_) { DIAG[row_]=x2; x2=0.f; } \
  if (cb+3==row_) { DIAG[row_]=x3; x3=0.f; } \
  PA.x=(_Float16)x0; PA.y=(_Float16)x1; \
  PB.x=(_Float16)x2; PB.y=(_Float16)x3; }

#define PACKROW(P, CP, DIAG) { \
  PACK4(P##0,  P##1,  c##CP##0, 0, DIAG) \
  PACK4(P##2,  P##3,  c##CP##1, 1, DIAG) \
  PACK4(P##4,  P##5,  c##CP##2, 2, DIAG) \
  PACK4(P##6,  P##7,  c##CP##3, 3, DIAG) \
  PACK4(P##8,  P##9,  c##CP##4, 4, DIAG) \
  PACK4(P##10, P##11, c##CP##5, 5, DIAG) \
  PACK4(P##12, P##13, c##CP##6, 6, DIAG) \
  PACK4(P##14, P##15, c##CP##7, 7, DIAG) }

// 16 fdot2 for one row (cols ascending; same accumulation order as R3)
#define DOTROW(ACC, P) \
  ACC = fdot2f(P##0,  PAIR(uh0,0), ACC); \
  ACC = fdot2f(P##1,  PAIR(uh0,1), ACC); \
  ACC = fdot2f(P##2,  PAIR(uh0,2), ACC); \
  ACC = fdot2f(P##3,  PAIR(uh0,3), ACC); \
  ACC = fdot2f(P##4,  PAIR(uh1,0), ACC); \
  ACC = fdot2f(P##5,  PAIR(uh1,1), ACC); \
  ACC = fdot2f(P##6,  PAIR(uh1,2), ACC); \
  ACC = fdot2f(P##7,  PAIR(uh1,3), ACC); \
  ACC = fdot2f(P##8,  PAIR(uh2,0), ACC); \
  ACC = fdot2f(P##9,  PAIR(uh2,1), ACC); \
  ACC = fdot2f(P##10, PAIR(uh2,2), ACC); \
  ACC = fdot2f(P##11, PAIR(uh2,3), ACC); \
  ACC = fdot2f(P##12, PAIR(uh3,0), ACC); \
  ACC = fdot2f(P##13, PAIR(uh3,1), ACC); \
  ACC = fdot2f(P##14, PAIR(uh3,2), ACC); \
  ACC = fdot2f(P##15, PAIR(uh3,3), ACC);

// 8-way partial combine (wave0), packed (g1, g2)
#define COMB(I) { \
  const int rr = 64 * (I) + lane; \
  float2 x0 = parts[rr],          x1 = parts[NN + rr]; \
  float2 x2 = parts[2*NN + rr],   x3 = parts[3*NN + rr]; \
  float2 x4 = parts[4*NN + rr],   x5 = parts[5*NN + rr]; \
  float2 x6 = parts[6*NN + rr],   x7 = parts[7*NN + rr]; \
  q1##I = ((x0.x+x1.x)+(x2.x+x3.x))+((x4.x+x5.x)+(x6.x+x7.x)); \
  q2##I = ((x0.y+x1.y)+(x2.y+x3.y))+((x4.y+x5.y)+(x6.y+x7.y)); }

__global__
__attribute__((amdgpu_flat_work_group_size(512, 512)))
__attribute__((amdgpu_waves_per_eu(1, 2)))
void mvo_kernel(const float* __restrict__ mu,
                const float* __restrict__ U,
                const float* __restrict__ A,
                float* __restrict__ out)
{
  __shared__ alignas(16) float2 parts[8 * NN];    // 16 KB; doubles as As staging
  __shared__ alignas(16) float    wsf[NN];        // w fp32
  __shared__ alignas(16) _Float16 whs[NN];        // w fp16
  __shared__ float mus[NN];
  __shared__ float diag1[NN];                     // fp32 diag of U^T U
  __shared__ float diag2[NN];                     // fp32 diag of A^T A
  __shared__ float dslot[8];
  __shared__ float slotA[8];
  __shared__ float slotB[8];
  __shared__ float taus;                          // warm-start tau
  __shared__ int   doneflag;

  float* As = (float*)parts;

  const int t    = threadIdx.x;
  const int b    = blockIdx.x;
  const int lane = t & 63;
  const int wv   = t >> 6;          // col-chunk 0..7 (32 cols each)

  const float* __restrict__ Ub = U + (size_t)b * NN * NN;
  const float* __restrict__ Ab = A + (size_t)b * NN * NN;

  if (t == 0) { doneflag = 0; taus = -1e30f; }
  if (t < NN) mus[t] = mu[b * NN + t];

  // G1 (U^TU) rows 64I+lane -> e I_; G2 (A^TA) -> h I_; cols [32wv,32wv+32)
  // as 16 loose half2 per row-group (col pair J = cols 32wv+2J, +1).
  DECLROW(e0_) DECLROW(e1_) DECLROW(e2_) DECLROW(e3_)
  DECLROW(h0_) DECLROW(h1_) DECLROW(h2_) DECLROW(h3_)
  float4 cA0,cA1,cA2,cA3,cA4,cA5,cA6,cA7;        // Gram accumulators
  float4 cB0,cB1,cB2,cB3,cB4,cB5,cB6,cB7;        // (only live in A-Gram)
  float fro, d1, d2;

  // ---- Gram: A^T A (2-group passes, low pressure), then U^T U (1-group x4)
  fro = 0.f;
  GRAM2(Ab, 0, 1);
  { const int row_ = lane;        PACKROW(h0_, A, diag2) }
  { const int row_ = 64 + lane;   PACKROW(h1_, B, diag2) }
  GRAM2(Ab, 128, 0);
  { const int row_ = 128 + lane;  PACKROW(h2_, A, diag2) }
  { const int row_ = 192 + lane;  PACKROW(h3_, B, diag2) }
  d2 = fro;                          // ||A||_F^2 partial
  fro = 0.f;
  GRAM1(Ub, 0, 1);
  { const int row_ = lane;        PACKROW(e0_, A, diag1) }
  GRAM1(Ub, 64, 0);
  { const int row_ = 64 + lane;   PACKROW(e1_, A, diag1) }
  GRAM1(Ub, 128, 0);
  { const int row_ = 128 + lane;  PACKROW(e2_, A, diag1) }
  GRAM1(Ub, 192, 0);
  { const int row_ = 192 + lane;  PACKROW(e3_, A, diag1) }
  d1 = fro;                          // ||U||_F^2 partial

  // step kept on the old shfl path (bitwise-stable vs R2/R3)
  #pragma unroll
  for (int m = 1; m < 64; m <<= 1) {
    d1 += __shfl_xor(d1, m, 64);
    d2 += __shfl_xor(d2, m, 64);
  }
  if (lane == 0) { slotA[wv] = d1; slotB[wv] = d2; }
  if (t < NN) { wsf[t] = 1.0f / 256.0f; whs[t] = (_Float16)(1.0f / 256.0f); }
  __syncthreads();
  float froU2 = 0.f, froA2 = 0.f;
  #pragma unroll
  for (int k = 0; k < 8; ++k) { froU2 += slotA[k]; froA2 += slotB[k]; }
  const float step = 1.0f / (froU2 + KAPPA_F * sqrtf(froA2) + 1.0f);

  const half8_t* whp = (const half8_t*)whs + 4 * wv;   // broadcast reads
  const int dsel = lane >> 5;

  // ---------------- PGD iterations (max 400, exact early exit) ------------
  #pragma unroll 1
  for (int it = 0; it < N_ITERS; ++it) {
    // Phase A: pure-register matvecs (128 v_dot2_f32_f16 / thread)
    half8_t uh0 = whp[0], uh1 = whp[1], uh2 = whp[2], uh3 = whp[3];
    float p10=0.f, p11=0.f, p12=0.f, p13=0.f;
    float p20=0.f, p21=0.f, p22=0.f, p23=0.f;
    DOTROW(p10, e0_) DOTROW(p11, e1_) DOTROW(p12, e2_) DOTROW(p13, e3_)
    DOTROW(p20, h0_) DOTROW(p21, h1_) DOTROW(p22, h2_) DOTROW(p23, h3_)

    // exact fp32 diagonal fold (each diag element exactly once across waves)
    float w_r0 = wsf[lane],       w_r1 = wsf[64 + lane];
    float w_r2 = wsf[128 + lane], w_r3 = wsf[192 + lane];
    if (wv == dsel)     { p10 = fmaf(diag1[lane],     w_r0, p10);
                          p20 = fmaf(diag2[lane],     w_r0, p20); }
    if (wv == 2 + dsel) { p11 = fmaf(diag1[64+lane],  w_r1, p11);
                          p21 = fmaf(diag2[64+lane],  w_r1, p21); }
    if (wv == 4 + dsel) { p12 = fmaf(diag1[128+lane], w_r2, p12);
                          p22 = fmaf(diag2[128+lane], w_r2, p22); }
    if (wv == 6 + dsel) { p13 = fmaf(diag1[192+lane], w_r3, p13);
                          p23 = fmaf(diag2[192+lane], w_r3, p23); }
    // dot(w, G2 w) partial folded into phase A (DPP reduce)
    float dpart = fmaf(p20, w_r0, fmaf(p21, w_r1, fmaf(p22, w_r2, p23 * w_r3)));
    dpart = wave_sum(dpart);
    parts[wv * NN + lane]       = make_float2(p10, p20);
    parts[wv * NN + 64 + lane]  = make_float2(p11, p21);
    parts[wv * NN + 128 + lane] = make_float2(p12, p22);
    parts[wv * NN + 192 + lane] = make_float2(p13, p23);
    if (lane == 0) dslot[wv] = dpart;
    __syncthreads();

    // Phase B: combine + grad + warm-started exact projection, wave 0 only
    if (wv == 0) {
      float q10, q11, q12, q13, q20, q21, q22, q23;
      COMB(0) COMB(1) COMB(2) COMB(3)
      float dot = ((dslot[0]+dslot[1])+(dslot[2]+dslot[3]))
                + ((dslot[4]+dslot[5])+(dslot[6]+dslot[7]));
      float nrm = sqrtf(fmaxf(dot, 1e-12f));
      float kon = KAPPA_F / nrm;
      float v0 = w_r0 - step * (q10 + kon * q20 - mus[lane]);
      float v1 = w_r1 - step * (q11 + kon * q21 - mus[64 + lane]);
      float v2 = w_r2 - step * (q12 + kon * q22 - mus[128 + lane]);
      float v3 = w_r3 - step * (q13 + kon * q23 - mus[192 + lane]);
      // Warm-started Michelot fixed-point. Break on stable count is EXACT:
      // nested threshold sets of equal size are equal; consistent set => KKT.
      // iter 0: taus = -1e30 -> first round == cold start (tau0=(sum-1)/256).
      float tau = taus;
      float cprev = -1.f;
      #pragma unroll 1
      for (int ms = 0; ms < 24; ++ms) {
        float s2 = (v0 > tau ? v0 : 0.f) + (v1 > tau ? v1 : 0.f)
                 + (v2 > tau ? v2 : 0.f) + (v3 > tau ? v3 : 0.f);
        float c2 = (v0 > tau ? 1.f : 0.f) + (v1 > tau ? 1.f : 0.f)
                 + (v2 > tau ? 1.f : 0.f) + (v3 > tau ? 1.f : 0.f);
        wave_sum2(s2, c2);
        if (c2 == cprev) break;
        tau = (s2 - 1.0f) / c2;      // c2=0 -> -inf -> self-healing restart
        cprev = c2;
      }
      float nw0 = fmaxf(v0 - tau, 0.f);
      float nw1 = fmaxf(v1 - tau, 0.f);
      float nw2 = fmaxf(v2 - tau, 0.f);
      float nw3 = fmaxf(v3 - tau, 0.f);
      int same = (nw0 == w_r0) && (nw1 == w_r1) && (nw2 == w_r2) && (nw3 == w_r3);
      int conv = __all(same);     // bitwise fixed point -> rest are identity
      wsf[lane]       = nw0; wsf[64 + lane]  = nw1;
      wsf[128 + lane] = nw2; wsf[192 + lane] = nw3;
      whs[lane]       = (_Float16)nw0; whs[64 + lane]  = (_Float16)nw1;
      whs[128 + lane] = (_Float16)nw2; whs[192 + lane] = (_Float16)nw3;
      if (lane == 0) { taus = tau; doneflag = conv; }
    }
    __syncthreads();
    if (doneflag) break;
  }

  // Final clamp (already >=0) + renormalize + store
  if (wv == 0) {
    float w_0 = wsf[lane],       w_1 = wsf[64 + lane];
    float w_2 = wsf[128 + lane], w_3 = wsf[192 + lane];
    float s = wave_sum(w_0 + w_1 + w_2 + w_3);
    float inv = 1.0f / (s + 1e-12f);
    float* ob = out + b * NN;
    ob[lane]        = w_0 * inv;
    ob[64 + lane]   = w_1 * inv;
    ob[128 + lane]  = w_2 * inv;
    ob[192 + lane]  = w_3 * inv;
  }
}

extern "C" void kernel_launch(void* const* d_in, const int* in_sizes, int n_in,
                              void* d_out, int out_size, void* d_ws, size_t ws_size,
                              hipStream_t stream) {
  const float* mu = (const float*)d_in[0];
  const float* U  = (const float*)d_in[1];
  const float* A  = (const float*)d_in[2];
  float* out = (float*)d_out;
  hipLaunchKernelGGL(mvo_kernel, dim3(NB), dim3(512), 0, stream, mu, U, A, out);
}